// Round 2
// baseline (948.360 us; speedup 1.0000x reference)
//
#include <hip/hip_runtime.h>
#include <hip/hip_fp16.h>

#define VIEWS 16
#define NN 256
#define STRIDE 262   // halves per LDS row: 524 B = 131 dwords -> bank shift 3/row
#define ROWS 259     // rows r = -1 .. 257  (index = r+1)
#define COLS 260     // cols c = -2 .. 257  (index = c+2)
#define LDS_HALFS (ROWS * STRIDE)   // 67,858 halves = 135,716 B

__launch_bounds__(1024, 1)
__global__ void fp_kernel(const float* __restrict__ vol, float* __restrict__ out) {
    __shared__ __half lds[LDS_HALFS];
    const int tid = threadIdx.x;
    const int z = blockIdx.x;

    // ---- zero entire LDS region (borders must be 0) ----
    uint32_t* lds32 = (uint32_t*)lds;
    const int NDW = (LDS_HALFS * 2) / 4;   // 33,929 dwords exactly
    for (int i = tid; i < NDW; i += 1024) lds32[i] = 0u;
    __syncthreads();

    // ---- stage slice z as fp16 into LDS interior ----
    const float* sp = vol + (size_t)z * (NN * NN);
    #pragma unroll
    for (int i = 0; i < 16; ++i) {
        int e = i * 4096 + tid * 4;            // element index in slice, %4==0
        float4 v4 = *(const float4*)(sp + e);  // 16B aligned
        int row = e >> 8;
        int col = e & 255;
        int base = (row + 1) * STRIDE + (col + 2);   // (col+2) even -> 4B aligned
        __half2* p = (__half2*)&lds[base];
        p[0] = __halves2half2(__float2half_rn(v4.x), __float2half_rn(v4.y));
        p[1] = __halves2half2(__float2half_rn(v4.z), __float2half_rn(v4.w));
    }
    __syncthreads();

    // ---- compute: wave = view, lanes over y, loop over x ----
    const int wave = tid >> 6;
    const int lane = tid & 63;
    const float ang = 0.017453292519943295f + (float)wave * 0.19634954084936207f;
    const float c = cosf(ang);
    const float s = sinf(ang);

    float acc[4];
    #pragma unroll
    for (int chunk = 0; chunk < 4; ++chunk) {
        const int y = chunk * 64 + lane;
        const float py = (float)y + 0.5f;
        // ixp = ix + 2 (col border offset), iyp = iy + 1 (row border offset)
        // ix = c*(x+0.5) - s*py + 128*(1-c+s) - 0.5
        // iy = s*(x+0.5) + c*py + 128*(1-s-c) - 0.5
        const float bx = -s * py + 128.0f * (1.0f - c + s) - 0.5f + 2.0f + 0.5f * c;
        const float by =  c * py + 128.0f * (1.0f - s - c) - 0.5f + 1.0f + 0.5f * s;
        float a = 0.0f;
        float xf = 0.0f;
        #pragma unroll 8
        for (int x = 0; x < NN; ++x) {
            float ixp = fmaf(c, xf, bx);
            float iyp = fmaf(s, xf, by);
            xf += 1.0f;
            // clamp: ix in [-1,256] -> ixp in [1,258]; iy in [-1,256] -> iyp in [0,257]
            ixp = fminf(fmaxf(ixp, 1.0f), 258.0f);
            iyp = fminf(fmaxf(iyp, 0.0f), 257.0f);
            int x0 = (int)ixp;                 // trunc == floor (positive)
            int y0 = (int)iyp;
            float wx = ixp - (float)x0;
            float wy = iyp - (float)y0;
            const __half* q = &lds[y0 * STRIDE + x0];
            float f00 = __half2float(q[0]);
            float f01 = __half2float(q[1]);
            float f10 = __half2float(q[STRIDE]);
            float f11 = __half2float(q[STRIDE + 1]);
            float h0 = fmaf(wx, f01 - f00, f00);
            float h1 = fmaf(wx, f11 - f10, f10);
            a += fmaf(wy, h1 - h0, h0);
        }
        acc[chunk] = a;
    }
    __syncthreads();

    // ---- transpose through LDS for coalesced output ----
    float* lout = (float*)lds;   // reuse slice buffer; 4096 floats
    #pragma unroll
    for (int chunk = 0; chunk < 4; ++chunk) {
        int y = chunk * 64 + lane;
        lout[y * VIEWS + wave] = acc[chunk];
    }
    __syncthreads();
    float4 r = *(float4*)&lout[tid * 4];
    float4* o4 = (float4*)(out + (size_t)z * (NN * VIEWS));
    o4[tid] = r;
}

extern "C" void kernel_launch(void* const* d_in, const int* in_sizes, int n_in,
                              void* d_out, int out_size, void* d_ws, size_t ws_size,
                              hipStream_t stream) {
    const float* vol = (const float*)d_in[0];
    float* out = (float*)d_out;
    fp_kernel<<<NN, 1024, 0, stream>>>(vol, out);
}

// Round 3
// 260.347 us; speedup vs baseline: 3.6427x; 3.6427x over previous
//
#include <hip/hip_runtime.h>
#include <hip/hip_fp16.h>

#define VIEWS 16
#define NN 256
#define DWS 131                     // dwords per LDS row (262 halves = cols -2..259)
#define STRIDE (2*DWS)              // halves per row
#define ROWS 259                    // rows y=-1..257 (index = y+1)
#define LDS_DW (ROWS*DWS)           // 33,929 dwords = 135,716 B

__launch_bounds__(1024, 1)
__global__ void fp_kernel(const float* __restrict__ vol, float* __restrict__ out) {
    __shared__ uint32_t lds[LDS_DW];
    const int tid = threadIdx.x;
    const int z = blockIdx.x;

    // ---- zero LDS (borders must be 0) ----
    for (int i = tid; i < LDS_DW; i += 1024) lds[i] = 0u;
    __syncthreads();

    // ---- stage slice z as fp16 (dword = 2 adjacent-x halves) ----
    __half* ldsH = (__half*)lds;
    const float* sp = vol + (size_t)z * (NN * NN);
    #pragma unroll
    for (int i = 0; i < 16; ++i) {
        int e = i * 4096 + tid * 4;            // %4 == 0
        float4 v4 = *(const float4*)(sp + e);
        int row = (e >> 8) + 1;
        int col = (e & 255) + 2;               // even -> dword-aligned
        __half2* p = (__half2*)&ldsH[row * STRIDE + col];
        p[0] = __halves2half2(__float2half_rn(v4.x), __float2half_rn(v4.y));
        p[1] = __halves2half2(__float2half_rn(v4.z), __float2half_rn(v4.w));
    }
    __syncthreads();

    // ---- compute: wave = view; lane owns 4 rays y = lane + 64r ----
    const int wave = tid >> 6;
    const int lane = tid & 63;
    const float ang = 0.017453292519943295f + (float)wave * 0.19634954084936207f;
    const float c = cosf(ang), s = sinf(ang);

    // ixp = c*(x+.5) - s*py + 128(1-c+s) - .5 + 2   (col border offset 2)
    // iyp = s*(x+.5) + c*py + 128(1-s-c) - .5 + 1   (row border offset 1)
    float bix[4], biy[4], acc[4];
    #pragma unroll
    for (int r = 0; r < 4; ++r) {
        float py = (float)(lane + 64 * r) + 0.5f;
        bix[r] = -s * py + 128.0f * (1.0f - c + s) + 1.5f + 0.5f * c;
        biy[r] =  c * py + 128.0f * (1.0f - s - c) + 0.5f + 0.5f * s;
        acc[r] = 0.0f;
    }

    float xf = 0.0f;
    #pragma unroll 2
    for (int x = 0; x < NN; ++x) {
        #pragma unroll
        for (int r = 0; r < 4; ++r) {
            float ix = fmaf(c, xf, bix[r]);
            float iy = fmaf(s, xf, biy[r]);
            ix = fminf(fmaxf(ix, 1.0f), 258.0f);   // -> v_med3
            iy = fminf(fmaxf(iy, 0.0f), 257.0f);
            int x0 = (int)ix;
            int y0 = (int)iy;
            float wx = ix - (float)x0;
            float wy = iy - (float)y0;
            int d0 = (y0 << 7) + (y0 << 1) + y0 + (x0 >> 1);   // y0*131 + x0/2
            // 4 dwords: rows y0,y0+1 x cols {2c,2c+1},{2c+2,2c+3}
            // pairs (d0, d0+131) and (d0+1, d0+132) -> 2x ds_read2_b32
            uint32_t lA = lds[d0];
            uint32_t lB = lds[d0 + DWS];
            uint32_t hA = lds[d0 + 1];
            uint32_t hB = lds[d0 + DWS + 1];
            uint32_t sh = (uint32_t)(x0 & 1) << 4;
            uint32_t r0 = __builtin_amdgcn_alignbit(hA, lA, sh);  // halves (x0, x0+1) row y0
            uint32_t r1 = __builtin_amdgcn_alignbit(hB, lB, sh);  // row y0+1
            union { uint32_t u; __half2 h; } u0, u1;
            u0.u = r0; u1.u = r1;
            float2 f0 = __half22float2(u0.h);
            float2 f1 = __half22float2(u1.h);
            float h0 = fmaf(wx, f0.y - f0.x, f0.x);
            float h1 = fmaf(wx, f1.y - f1.x, f1.x);
            acc[r] += fmaf(wy, h1 - h0, h0);
        }
        xf += 1.0f;
    }
    __syncthreads();

    // ---- transpose through LDS for coalesced float4 output ----
    float* lout = (float*)lds;   // 4096 floats
    #pragma unroll
    for (int r = 0; r < 4; ++r) {
        int y = 64 * r + lane;
        lout[y * VIEWS + wave] = acc[r];
    }
    __syncthreads();
    float4 v = *(float4*)&lout[tid * 4];
    float4* o4 = (float4*)(out + (size_t)z * (NN * VIEWS));
    o4[tid] = v;
}

extern "C" void kernel_launch(void* const* d_in, const int* in_sizes, int n_in,
                              void* d_out, int out_size, void* d_ws, size_t ws_size,
                              hipStream_t stream) {
    const float* vol = (const float*)d_in[0];
    float* out = (float*)d_out;
    fp_kernel<<<NN, 1024, 0, stream>>>(vol, out);
}